// Round 3
// baseline (68.140 us; speedup 1.0000x reference)
//
#include <hip/hip_runtime.h>
#include <math.h>

#define NV 512
#define NF 1024
#define IMS 256
#define TILE 8
#define TPD (IMS / TILE)      // 32 tiles per dim
#define NT (TPD * TPD)        // 1024 tiles
constexpr float SIGMA = 0.003f;
constexpr float LOG2E = 1.4426950408889634f;
constexpr float PXSZ = 2.0f / (float)IMS;          // pixel size in NDC
constexpr float TILE_R = 3.5f * PXSZ;              // max |pixel-center - tile-center|

#if __has_builtin(__builtin_amdgcn_exp2f)
#define EXP2(x) __builtin_amdgcn_exp2f(x)
#else
#define EXP2(x) exp2f(x)
#endif

// ---------------- projection: 512 vertices -> 2D NDC ----------------
__global__ void project_kernel(const float* __restrict__ verts, float* __restrict__ xy) {
    int i = blockIdx.x * blockDim.x + threadIdx.x;
    if (i >= NV) return;
    const float deg2rad = 0.017453292519943295f;
    float e = 0.0f * deg2rad;
    float a = 90.0f * deg2rad;
    float ce = cosf(e), se = sinf(e), ca = cosf(a), sa = sinf(a);
    float ex = 2.732f * ce * sa, ey = 2.732f * se, ez = -2.732f * ce * ca;
    float zn = sqrtf(ex*ex + ey*ey + ez*ez) + 1e-12f;
    float zx = -ex/zn, zy = -ey/zn, zz = -ez/zn;
    float cx = 1.0f*zz, cy = 0.0f, cz = -1.0f*zx;
    float xn = sqrtf(cx*cx + cy*cy + cz*cz) + 1e-12f;
    float xax_x = cx/xn, xax_y = cy/xn, xax_z = cz/xn;
    float yx = zy*xax_z - zz*xax_y;
    float yy = zz*xax_x - zx*xax_z;
    float yz = zx*xax_y - zy*xax_x;
    float w = tanf(30.0f * deg2rad);
    float vx = verts[i*3+0] - ex, vy = verts[i*3+1] - ey, vz = verts[i*3+2] - ez;
    float camx = xax_x*vx + xax_y*vy + xax_z*vz;
    float camy = yx*vx + yy*vy + yz*vz;
    float camz = zx*vx + zy*vy + zz*vz;
    float z = fmaxf(camz, 0.01f);
    float invzw = 1.0f / (z * w);
    xy[i*2+0] = camx * invzw;
    xy[i*2+1] = camy * invzw;
}

// ---------------- per-face edge-line coefficients ----------------
// d_edge(px,py) = A*px + B*py + C with sign(area), 1/|e|, 1/SIGMA, log2(e) folded.
__global__ void face_kernel(const float* __restrict__ xy, const int* __restrict__ faces,
                            float* __restrict__ coef) {
    int f = blockIdx.x * blockDim.x + threadIdx.x;
    if (f >= NF) return;
    int i0 = faces[f*3+0], i1 = faces[f*3+1], i2 = faces[f*3+2];
    float ax = xy[i0*2], ay = xy[i0*2+1];
    float bx = xy[i1*2], by = xy[i1*2+1];
    float cx = xy[i2*2], cy = xy[i2*2+1];
    float area = (bx-ax)*(cy-ay) - (by-ay)*(cx-ax);
    float s = (area >= 0.0f) ? 1.0f : -1.0f;
    float pxs[3] = {ax,bx,cx}, pys[3] = {ay,by,cy};
    float o[9];
    #pragma unroll
    for (int k = 0; k < 3; ++k) {
        float x0 = pxs[k],       y0 = pys[k];
        float x1 = pxs[(k+1)%3], y1 = pys[(k+1)%3];
        float ex_ = x1 - x0, ey_ = y1 - y0;
        float len = sqrtf(ex_*ex_ + ey_*ey_);
        float inv = s * (LOG2E / SIGMA) / (len + 1e-12f);
        o[k*3+0] = -ey_ * inv;
        o[k*3+1] =  ex_ * inv;
        o[k*3+2] = (ey_*x0 - ex_*y0) * inv;
    }
    float* dst = coef + f*12;
    #pragma unroll
    for (int k = 0; k < 9; ++k) dst[k] = o[k];
    dst[9] = dst[10] = dst[11] = 0.0f;
}

// ---------------- per-tile binning: active list + covered flag ----------------
__global__ __launch_bounds__(256) void bin_kernel(const float* __restrict__ coef,
                                                  unsigned short* __restrict__ lists,
                                                  int* __restrict__ tlen,
                                                  int* __restrict__ tcov) {
    int tile = blockIdx.x;
    int ti = tile / TPD, tj = tile % TPD;
    float cxn = ((float)(tj * TILE) + 4.0f) * PXSZ - 1.0f;   // tile center x (NDC)
    float cyn = -(((float)(ti * TILE) + 4.0f) * PXSZ - 1.0f);// tile center y (NDC)
    __shared__ int cnt, cov;
    if (threadIdx.x == 0) { cnt = 0; cov = 0; }
    __syncthreads();
    const float4* c4 = (const float4*)coef;
    #pragma unroll
    for (int k = 0; k < NF / 256; ++k) {
        int f = threadIdx.x + 256 * k;
        float4 c0 = c4[f*3+0];
        float4 c1 = c4[f*3+1];
        float4 c2 = c4[f*3+2];
        float d0 = fmaf(c0.x, cxn, fmaf(c0.y, cyn, c0.z));
        float r0 = (fabsf(c0.x) + fabsf(c0.y)) * TILE_R;
        float d1 = fmaf(c0.w, cxn, fmaf(c1.x, cyn, c1.y));
        float r1 = (fabsf(c0.w) + fabsf(c1.x)) * TILE_R;
        float d2 = fmaf(c1.z, cxn, fmaf(c1.w, cyn, c2.x));
        float r2 = (fabsf(c1.z) + fabsf(c1.w)) * TILE_R;
        float t_hi = fminf(d0 + r0, fminf(d1 + r1, d2 + r2));
        float t_lo = fminf(d0 - r0, fminf(d1 - r1, d2 - r2));
        if (t_lo > 130.0f) atomicOr(&cov, 1);          // factor exactly 0 tile-wide
        else if (t_hi > -26.0f) {                       // factor != 1 somewhere
            int pos = atomicAdd(&cnt, 1);
            lists[(size_t)tile * NF + pos] = (unsigned short)f;
        }
    }
    __syncthreads();
    if (threadIdx.x == 0) { tlen[tile] = cnt; tcov[tile] = cov; }
}

// ---------------- rasterize per tile (one wave) + fused loss ----------------
__global__ __launch_bounds__(64) void raster_kernel(const float* __restrict__ coef,
                                                    const unsigned short* __restrict__ lists,
                                                    const int* __restrict__ tlen,
                                                    const int* __restrict__ tcov,
                                                    const float* __restrict__ img,
                                                    float* __restrict__ out) {
    int tile = blockIdx.x;
    int ti = tile / TPD, tj = tile % TPD;
    int lane = threadIdx.x;
    int pi = ti * TILE + (lane >> 3);
    int pj = tj * TILE + (lane & 7);
    float px = ((float)pj + 0.5f) * PXSZ - 1.0f;
    float py = -(((float)pi + 0.5f) * PXSZ - 1.0f);
    float prod = 1.0f;
    if (tcov[tile]) {
        prod = 0.0f;
    } else {
        int len = tlen[tile];
        const float4* c4 = (const float4*)coef;
        const unsigned short* lst = lists + (size_t)tile * NF;
        for (int k = 0; k < len; ++k) {
            int f = (int)lst[k];
            float4 c0 = c4[f*3+0];
            float4 c1 = c4[f*3+1];
            float4 c2 = c4[f*3+2];
            float d0 = fmaf(c0.x, px, fmaf(c0.y, py, c0.z));
            float d1 = fmaf(c0.w, px, fmaf(c1.x, py, c1.y));
            float d2 = fmaf(c1.z, px, fmaf(c1.w, py, c2.x));
            float t = fminf(d0, fminf(d1, d2));
            float ef = EXP2(t);                            // overflow -> inf
            prod *= __builtin_amdgcn_rcpf(1.0f + ef);      // rcp(inf) -> 0
            if ((k & 7) == 7 && __ballot(prod > 0.0f) == 0ull) break;
        }
    }
    float sil = 1.0f - prod;
    float diff = sil - img[pi * IMS + pj];
    float v = diff * diff;
    #pragma unroll
    for (int o = 32; o > 0; o >>= 1) v += __shfl_down(v, o);
    if (lane == 0) atomicAdd(out, v);
}

extern "C" void kernel_launch(void* const* d_in, const int* in_sizes, int n_in,
                              void* d_out, int out_size, void* d_ws, size_t ws_size,
                              hipStream_t stream) {
    const float* verts = (const float*)d_in[0];
    const float* img   = (const float*)d_in[1];
    const int*   faces = (const int*)d_in[2];
    float* out = (float*)d_out;
    char* ws = (char*)d_ws;
    float* xy             = (float*)(ws);                    // 4 KB
    float* coef           = (float*)(ws + 4096);             // 48 KB
    int*   tlen           = (int*)(ws + 4096 + 49152);       // 4 KB
    int*   tcov           = (int*)(ws + 4096 + 49152 + 4096);// 4 KB
    unsigned short* lists = (unsigned short*)(ws + 4096 + 49152 + 8192); // 2 MB

    hipMemsetAsync(out, 0, sizeof(float), stream);
    project_kernel<<<2, 256, 0, stream>>>(verts, xy);
    face_kernel<<<4, 256, 0, stream>>>(xy, faces, coef);
    bin_kernel<<<NT, 256, 0, stream>>>(coef, lists, tlen, tcov);
    raster_kernel<<<NT, 64, 0, stream>>>(coef, lists, tlen, tcov, img, out);
}

// Round 4
// 28.970 us; speedup vs baseline: 2.3521x; 2.3521x over previous
//
#include <hip/hip_runtime.h>
#include <math.h>

#define NV 512
#define NF 1024
#define IMS 256
#define TILE 8
#define TPD 32            // tiles per dim
#define NT 1024           // total tiles
#define CHUNK 256         // faces staged in LDS per round
constexpr float SIGMA = 0.003f;
constexpr float LOG2E = 1.4426950408889634f;
constexpr float PXSZ = 2.0f / (float)IMS;
constexpr float TILE_R = 3.5f * PXSZ;   // max |pixel-center - tile-center|

#if __has_builtin(__builtin_amdgcn_exp2f)
#define EXP2(x) __builtin_amdgcn_exp2f(x)
#else
#define EXP2(x) exp2f(x)
#endif

// ---- fused: per-face vertex projection + edge coefficients + out zeroing ----
// d_edge(px,py) = A*px + B*py + C with sign(area), 1/|e|, 1/SIGMA, log2(e) folded.
__global__ __launch_bounds__(256) void prep_kernel(const float* __restrict__ verts,
                                                   const int* __restrict__ faces,
                                                   float* __restrict__ coef,
                                                   float* __restrict__ out) {
    int f = blockIdx.x * 256 + threadIdx.x;
    if (f == 0) out[0] = 0.0f;
    if (f >= NF) return;

    // camera (all compile-time-ish scalar math, ~30 ops)
    const float deg2rad = 0.017453292519943295f;
    float e = 0.0f * deg2rad, a = 90.0f * deg2rad;
    float ce = cosf(e), se = sinf(e), ca = cosf(a), sa = sinf(a);
    float ex = 2.732f * ce * sa, ey = 2.732f * se, ez = -2.732f * ce * ca;
    float zn = sqrtf(ex*ex + ey*ey + ez*ez) + 1e-12f;
    float zx = -ex/zn, zy = -ey/zn, zz = -ez/zn;
    float cx = 1.0f*zz, cyv = 0.0f, cz = -1.0f*zx;   // cross(up, zax), up=(0,1,0)
    float xn = sqrtf(cx*cx + cyv*cyv + cz*cz) + 1e-12f;
    float xax_x = cx/xn, xax_y = cyv/xn, xax_z = cz/xn;
    float yx = zy*xax_z - zz*xax_y;
    float yy = zz*xax_x - zx*xax_z;
    float yz = zx*xax_y - zy*xax_x;
    float w = tanf(30.0f * deg2rad);

    int i0 = faces[f*3+0], i1 = faces[f*3+1], i2 = faces[f*3+2];
    float P[3][2];
    int idx[3] = {i0, i1, i2};
    #pragma unroll
    for (int k = 0; k < 3; ++k) {
        float vx = verts[idx[k]*3+0] - ex;
        float vy = verts[idx[k]*3+1] - ey;
        float vz = verts[idx[k]*3+2] - ez;
        float camx = xax_x*vx + xax_y*vy + xax_z*vz;
        float camy = yx*vx + yy*vy + yz*vz;
        float camz = zx*vx + zy*vy + zz*vz;
        float z = fmaxf(camz, 0.01f);
        float invzw = 1.0f / (z * w);
        P[k][0] = camx * invzw;
        P[k][1] = camy * invzw;
    }
    float area = (P[1][0]-P[0][0])*(P[2][1]-P[0][1]) - (P[1][1]-P[0][1])*(P[2][0]-P[0][0]);
    float s = (area >= 0.0f) ? 1.0f : -1.0f;
    float o[9];
    #pragma unroll
    for (int k = 0; k < 3; ++k) {
        float x0 = P[k][0],       y0 = P[k][1];
        float x1 = P[(k+1)%3][0], y1 = P[(k+1)%3][1];
        float ex_ = x1 - x0, ey_ = y1 - y0;
        float len = sqrtf(ex_*ex_ + ey_*ey_);
        float inv = s * (LOG2E / SIGMA) / (len + 1e-12f);
        o[k*3+0] = -ey_ * inv;
        o[k*3+1] =  ex_ * inv;
        o[k*3+2] = (ey_*x0 - ex_*y0) * inv;
    }
    float* dst = coef + f*12;
    #pragma unroll
    for (int k = 0; k < 9; ++k) dst[k] = o[k];
    dst[9] = dst[10] = dst[11] = 0.0f;
}

// ---- fused bin + stage + rasterize + loss: one block (4 waves) per 8x8 tile ----
__global__ __launch_bounds__(256) void raster_kernel(const float* __restrict__ coef,
                                                     const float* __restrict__ img,
                                                     float* __restrict__ out) {
    __shared__ unsigned short slist[NF];   // 2 KB
    __shared__ float4 scoef[CHUNK * 3];    // 12 KB
    __shared__ float part[4][64];          // 1 KB
    __shared__ int cnt, cov, done;
    int t = threadIdx.x;
    int tile = blockIdx.x;
    int ti = tile >> 5, tj = tile & 31;
    if (t == 0) { cnt = 0; cov = 0; done = 0; }
    __syncthreads();

    const float4* c4 = (const float4*)coef;
    // ---- bin: cull faces vs this tile (4 rounds x 256 threads) ----
    float cxn = ((float)(tj * TILE) + 4.0f) * PXSZ - 1.0f;
    float cyn = -(((float)(ti * TILE) + 4.0f) * PXSZ - 1.0f);
    #pragma unroll
    for (int k = 0; k < NF / 256; ++k) {
        int f = t + 256 * k;
        float4 c0 = c4[f*3+0];
        float4 c1 = c4[f*3+1];
        float4 c2 = c4[f*3+2];
        float d0 = fmaf(c0.x, cxn, fmaf(c0.y, cyn, c0.z));
        float r0 = (fabsf(c0.x) + fabsf(c0.y)) * TILE_R;
        float d1 = fmaf(c0.w, cxn, fmaf(c1.x, cyn, c1.y));
        float r1 = (fabsf(c0.w) + fabsf(c1.x)) * TILE_R;
        float d2 = fmaf(c1.z, cxn, fmaf(c1.w, cyn, c2.x));
        float r2 = (fabsf(c1.z) + fabsf(c1.w)) * TILE_R;
        float t_hi = fminf(d0 + r0, fminf(d1 + r1, d2 + r2));
        float t_lo = fminf(d0 - r0, fminf(d1 - r1, d2 - r2));
        if (t_lo > 130.0f) atomicOr(&cov, 1);            // factor exactly 0 tile-wide
        else if (t_hi > -26.0f) {                         // factor != 1 somewhere in tile
            int pos = atomicAdd(&cnt, 1);
            slist[pos] = (unsigned short)f;
        }
    }
    __syncthreads();

    int lane = t & 63, wave = t >> 6;
    int pi = ti * TILE + (lane >> 3);
    int pj = tj * TILE + (lane & 7);
    float px = ((float)pj + 0.5f) * PXSZ - 1.0f;
    float py = -(((float)pi + 0.5f) * PXSZ - 1.0f);
    float prod = 1.0f;
    int covered = cov;   // uniform after barrier
    if (!covered) {
        int len = cnt;
        for (int base = 0; base < len; base += CHUNK) {
            int m = min(CHUNK, len - base);
            // parallel gather of surviving faces' coefs into LDS
            if (t < m) {
                int f = (int)slist[base + t];
                scoef[t*3+0] = c4[f*3+0];
                scoef[t*3+1] = c4[f*3+1];
                scoef[t*3+2] = c4[f*3+2];
            }
            __syncthreads();
            // each wave covers all 64 pixels; faces strided across 4 waves
            int it = 0;
            for (int j = wave; j < m; j += 4) {
                float4 c0 = scoef[j*3+0];    // LDS broadcast (same addr all lanes)
                float4 c1 = scoef[j*3+1];
                float4 c2 = scoef[j*3+2];
                float d0 = fmaf(c0.x, px, fmaf(c0.y, py, c0.z));
                float d1 = fmaf(c0.w, px, fmaf(c1.x, py, c1.y));
                float d2 = fmaf(c1.z, px, fmaf(c1.w, py, c2.x));
                float tm = fminf(d0, fminf(d1, d2));
                float ef = EXP2(tm);                          // overflow -> inf
                prod *= __builtin_amdgcn_rcpf(1.0f + ef);     // rcp(inf) -> 0
                if ((++it & 7) == 0 && __ballot(prod > 0.0f) == 0ull) {
                    atomicOr(&done, 1);   // my partial is 0 for all 64 pixels -> final is 0
                    break;
                }
            }
            __syncthreads();              // all waves finished reading scoef
            if (done) break;              // uniform after barrier
        }
    }
    part[wave][lane] = prod;
    __syncthreads();

    if (wave == 0) {
        float pr = covered ? 0.0f
                 : part[0][lane] * part[1][lane] * part[2][lane] * part[3][lane];
        float sil = 1.0f - pr;
        float diff = sil - img[pi * IMS + pj];
        float v = diff * diff;
        #pragma unroll
        for (int o = 32; o > 0; o >>= 1) v += __shfl_down(v, o);
        if (lane == 0) atomicAdd(out, v);
    }
}

extern "C" void kernel_launch(void* const* d_in, const int* in_sizes, int n_in,
                              void* d_out, int out_size, void* d_ws, size_t ws_size,
                              hipStream_t stream) {
    const float* verts = (const float*)d_in[0];
    const float* img   = (const float*)d_in[1];
    const int*   faces = (const int*)d_in[2];
    float* out  = (float*)d_out;
    float* coef = (float*)d_ws;   // 12288 floats = 48 KB

    prep_kernel<<<4, 256, 0, stream>>>(verts, faces, coef, out);
    raster_kernel<<<NT, 256, 0, stream>>>(coef, img, out);
}